// Round 5
// baseline (198.559 us; speedup 1.0000x reference)
//
#include <hip/hip_runtime.h>
#include <hip/hip_bf16.h>

// Problem constants (from reference): z [65536,256] f32, embeddings [1024,256] f32
// out = quantized_st [65536*256] f32 ++ loss scalar (out_size = 16777217)
#define NROWS 65536
#define DIM   256
#define KCB   1024
#define ND    (NROWS * DIM)

typedef float f32x4  __attribute__((ext_vector_type(4)));
typedef short bf16x8 __attribute__((ext_vector_type(8)));  // 8 bf16 in 4 VGPRs
typedef short bf16x4 __attribute__((ext_vector_type(4)));  // 4 bf16 in 2 VGPRs

// workspace layout (bytes)
#define WS_LOSS   0      // float
#define WS_TICKET 64     // unsigned
#define WS_ENORM  256    // float[1024]
#define WS_E      8192   // bf16 permuted [16 chunks][2048 ids][8] = 512 KiB
// total needed: 8192 + 524288 = 532480 B

// fp32 -> bf16 bits, round-to-nearest-even
static __device__ __forceinline__ short f2bf(float f) {
    union { float f; unsigned u; } v; v.f = f;
    unsigned u = v.u;
    unsigned r = (u + 0x7fffu + ((u >> 16) & 1u)) >> 16;
    return (short)(unsigned short)r;
}

static __device__ __forceinline__ unsigned f2u(float f) {
    union { float f; unsigned u; } v; v.f = f; return v.u;
}
static __device__ __forceinline__ float u2f(unsigned u) {
    union { unsigned u; float f; } v; v.u = u; return v.f;
}

// ---------------------------------------------------------------------------
// Prep: e_norm (fp32) + E converted to bf16 in MFMA-streaming-permuted order.
// Permuted id within a 64-row chunk: id = (t*8+s)*64 + q*16 + l
//   where embedding row = t*16+l, d-chunk c = s*4+q (8 bf16 per chunk).
// 256 blocks; each block owns 4 rows; each thread reads ONE coalesced
// float4 (16 B/lane), wave-reduces the row norm, writes its 8-B half-chunk.
// ---------------------------------------------------------------------------
__global__ __launch_bounds__(256) void prep_e(const float* __restrict__ E,
                                              float* __restrict__ enorm,
                                              bf16x4* __restrict__ wsE2,
                                              float* __restrict__ loss_acc,
                                              unsigned* __restrict__ ticket) {
    const int tid = threadIdx.x;
    const int blk = blockIdx.x;            // 0..255, 4 embedding rows each

    if (blk == 0 && tid == 0) { *loss_acc = 0.f; *ticket = 0u; }

    const int w    = tid >> 6;             // 0..3: row within this block
    const int lane = tid & 63;             // float4 index within the row
    const int row  = blk * 4 + w;

    float4 f = ((const float4*)E)[row * 64 + lane];

    // row norm: each wave holds exactly one row -> full-wave butterfly
    float s = f.x * f.x + f.y * f.y + f.z * f.z + f.w * f.w;
#pragma unroll
    for (int m = 1; m < 64; m <<= 1) s += __shfl_xor(s, m, 64);
    if (lane == 0) enorm[row] = s;

    // permuted bf16 half-chunk write (8 B per lane; lane pairs are 16-B contiguous)
    bf16x4 o;
    o[0] = f2bf(f.x); o[1] = f2bf(f.y); o[2] = f2bf(f.z); o[3] = f2bf(f.w);
    const int kc = row >> 6;               // 64-row chunk
    const int rg = row & 63;
    const int t  = rg >> 4, l = rg & 15;
    const int c    = lane >> 1;            // 8-elem d-chunk 0..31
    const int half = lane & 1;
    const int sC   = c >> 2, q = c & 3;
    const int id   = (t * 8 + sC) * 64 + q * 16 + l;
    wsE2[(kc * 2048 + id) * 2 + half] = o;
}

// ---------------------------------------------------------------------------
// Main: fused score-GEMM (bf16 MFMA) + argmin + gather + loss.
// Block = 256 thr (4 waves), 128 z-rows. Wave w owns rows w*32..w*32+31 as
// 2 row-tiles of 16; A-fragments live in registers for the whole K sweep.
//
// ROUND-5 = ROUND-4 design, resubmitted after an infra-only failure
// ("container failed twice"; no kernel verdict). Evidence base (R0-R3):
// occupancy halves when VGPR>128; LDS pipe ~37% of chunk wall; barriers
// serialize pipes.
//  1. NO LDS STAGING. B-fragments stream directly from wsE (L2-resident,
//     512 KB/XCD; a 32 KB chunk also fits L1). Removes all 32 K-loop
//     barriers, the whole ds_write/ds_read pipe, and the exposed stage
//     latency. L2 floor: 2048 waves x 512 KB = 1 GB @ 34.5 TB/s ~ 29 us.
//  2. PACKED ARGMIN KEYS. Score biased positive (sc' = (en+1) - 2 z.e in
//     [0.4,1.6]) so float order == unsigned order; low 10 mantissa bits
//     replaced by the embedding index. One v_min_u32 carries value+index:
//     kills mini[2][4] (-8 VGPRs) and the cmp+2xcndmask update. Truncation
//     noise (<=1.2e-4) is the same order as the bf16 score noise the
//     harness already accepts (absmax sits at 2/K = near-tie flips).
//     Ties resolve to lowest index automatically, matching argmin.
//  3. __launch_bounds__(256, 2): pin allocator to the 2-waves/SIMD budget
//     (the proven cliff: 120 VGPR -> 2 blocks/CU, 136 -> 1 block/CU).
// ---------------------------------------------------------------------------
__global__ __launch_bounds__(256, 2) void vq_main(const float* __restrict__ Z,
                                                  const float* __restrict__ E,
                                                  const float* __restrict__ enorm,
                                                  const bf16x8* __restrict__ wsE,
                                                  float* __restrict__ out,
                                                  float* __restrict__ loss_acc,
                                                  unsigned* __restrict__ ticket) {
    __shared__ float enorm_s[KCB];      // 4 KiB: all 1024 norms, pre-biased +1.0
    __shared__ float znorm_s[128];
    __shared__ int   closest_s[128];
    __shared__ float blk_loss;

    const int tid  = threadIdx.x;
    const int w    = tid >> 6;
    const int lane = tid & 63;
    const int q    = lane >> 4;
    const int l    = lane & 15;
    const int blk  = blockIdx.x;

    if (tid == 0) blk_loss = 0.f;

    // whole e-norm table once, biased by +1.0 for the positive-score trick
    {
        float4 e4 = ((const float4*)enorm)[tid];
        e4.x += 1.f; e4.y += 1.f; e4.z += 1.f; e4.w += 1.f;
        ((float4*)enorm_s)[tid] = e4;
    }

    // ---- load A fragments (z rows) into registers; accumulate ||z||^2 fp32 ----
    bf16x8 zf[2][8];
    const float4* Z4 = (const float4*)Z;
#pragma unroll
    for (int rt = 0; rt < 2; ++rt) {
        int row = blk * 128 + w * 32 + rt * 16 + l;
        float zn = 0.f;
#pragma unroll
        for (int s = 0; s < 8; ++s) {
            int fi = row * 64 + s * 8 + q * 2;
            float4 f0 = Z4[fi], f1 = Z4[fi + 1];
            zn += f0.x * f0.x + f0.y * f0.y + f0.z * f0.z + f0.w * f0.w;
            zn += f1.x * f1.x + f1.y * f1.y + f1.z * f1.z + f1.w * f1.w;
            bf16x8 o;
            o[0] = f2bf(f0.x); o[1] = f2bf(f0.y); o[2] = f2bf(f0.z); o[3] = f2bf(f0.w);
            o[4] = f2bf(f1.x); o[5] = f2bf(f1.y); o[6] = f2bf(f1.z); o[7] = f2bf(f1.w);
            zf[rt][s] = o;
        }
        // each lane holds 64 of the row's 256 values; sum across the 4 q-lanes
        zn += __shfl_xor(zn, 16, 64);
        zn += __shfl_xor(zn, 32, 64);
        if (q == 0) znorm_s[w * 32 + rt * 16 + l] = zn;
    }

    // packed running argmin: high 22 bits = biased-score bits, low 10 = kidx
    unsigned minp[2][4];
#pragma unroll
    for (int rt = 0; rt < 2; ++rt)
#pragma unroll
        for (int r = 0; r < 4; ++r) minp[rt][r] = 0xFFFFFFFFu;

    __syncthreads();   // enorm_s (and blk_loss init) visible to all waves

    // ---- K sweep: flat stream, NO barriers. B-frags read from L1/L2. ----
    for (int kc = 0; kc < 16; ++kc) {
        const bf16x8* __restrict__ Ec = wsE + kc * 2048;

        f32x4 acc[2][4];
#pragma unroll
        for (int rt = 0; rt < 2; ++rt)
#pragma unroll
            for (int t = 0; t < 4; ++t) acc[rt][t] = (f32x4){0.f, 0.f, 0.f, 0.f};

#pragma unroll
        for (int s = 0; s < 8; ++s) {
            bf16x8 b0 = Ec[(0 * 8 + s) * 64 + lane];
            bf16x8 b1 = Ec[(1 * 8 + s) * 64 + lane];
            bf16x8 b2 = Ec[(2 * 8 + s) * 64 + lane];
            bf16x8 b3 = Ec[(3 * 8 + s) * 64 + lane];
            acc[0][0] = __builtin_amdgcn_mfma_f32_16x16x32_bf16(zf[0][s], b0, acc[0][0], 0, 0, 0);
            acc[0][1] = __builtin_amdgcn_mfma_f32_16x16x32_bf16(zf[0][s], b1, acc[0][1], 0, 0, 0);
            acc[0][2] = __builtin_amdgcn_mfma_f32_16x16x32_bf16(zf[0][s], b2, acc[0][2], 0, 0, 0);
            acc[0][3] = __builtin_amdgcn_mfma_f32_16x16x32_bf16(zf[0][s], b3, acc[0][3], 0, 0, 0);
            acc[1][0] = __builtin_amdgcn_mfma_f32_16x16x32_bf16(zf[1][s], b0, acc[1][0], 0, 0, 0);
            acc[1][1] = __builtin_amdgcn_mfma_f32_16x16x32_bf16(zf[1][s], b1, acc[1][1], 0, 0, 0);
            acc[1][2] = __builtin_amdgcn_mfma_f32_16x16x32_bf16(zf[1][s], b2, acc[1][2], 0, 0, 0);
            acc[1][3] = __builtin_amdgcn_mfma_f32_16x16x32_bf16(zf[1][s], b3, acc[1][3], 0, 0, 0);
        }

        // min update: C/D layout col = lane&15 (embedding), row = q*4+reg (z row)
        // sc' = (en+1) - 2*dot  in (0.4, 1.6)  ->  positive: u32 order = f32 order
#pragma unroll
        for (int t = 0; t < 4; ++t) {
            float    en   = enorm_s[kc * 64 + t * 16 + l];     // pre-biased +1
            unsigned kidx = (unsigned)(kc * 64 + t * 16 + l);  // < 1024
#pragma unroll
            for (int rt = 0; rt < 2; ++rt)
#pragma unroll
                for (int r = 0; r < 4; ++r) {
                    float sc = __builtin_fmaf(-2.f, acc[rt][t][r], en);
                    unsigned key = (f2u(sc) & 0xFFFFFC00u) | kidx;
                    minp[rt][r] = key < minp[rt][r] ? key : minp[rt][r];
                }
        }
    }

    // ---- cross-lane argmin: u32 min over the 16 column-lanes of each quad ----
    float lossp = 0.f;
#pragma unroll
    for (int rt = 0; rt < 2; ++rt)
#pragma unroll
        for (int r = 0; r < 4; ++r) {
            unsigned p = minp[rt][r];
#pragma unroll
            for (int m = 1; m <= 8; m <<= 1) {
                unsigned op = (unsigned)__shfl_xor((int)p, m, 64);
                p = op < p ? op : p;
            }
            if (l == 0) {
                int rloc = w * 32 + rt * 16 + q * 4 + r;
                closest_s[rloc] = (int)(p & 1023u);
                float v = u2f(p & 0xFFFFFC00u) - 1.0f;
                lossp += v + znorm_s[rloc];   // ||z||^2 + ||e*||^2 - 2 z.e*
            }
        }
    if (l == 0) atomicAdd(&blk_loss, lossp);
    __syncthreads();                      // closest_s + blk_loss visible

    // ---- gather epilogue: out rows = E[closest] in fp32 (exact values) ----
    const float4* E4 = (const float4*)E;
    float4* O4 = (float4*)out;
#pragma unroll
    for (int u = 0; u < 32; ++u) {
        int idx = u * 256 + tid;          // 0..8191
        int row = idx >> 6;
        int c4  = idx & 63;
        int k   = closest_s[row];
        O4[(blk * 128 + row) * 64 + c4] = E4[k * 64 + c4];
    }

    // ---- loss finalize: last block through the ticket writes the scalar ----
    if (tid == 0) {
        atomicAdd(loss_acc, blk_loss);
        __threadfence();                  // loss add visible before ticket bump
        unsigned tk = atomicAdd(ticket, 1u);
        if (tk == (unsigned)(gridDim.x - 1)) {
            float total = atomicAdd(loss_acc, 0.0f);   // coherent read of final sum
            out[ND] = 1.25f * total / (float)ND;       // codebook + 0.25*commitment
        }
    }
}

extern "C" void kernel_launch(void* const* d_in, const int* in_sizes, int n_in,
                              void* d_out, int out_size, void* d_ws, size_t ws_size,
                              hipStream_t stream) {
    const float* z = (const float*)d_in[0];
    const float* e = (const float*)d_in[1];
    float* out = (float*)d_out;
    char*  ws  = (char*)d_ws;
    float*    loss_acc = (float*)(ws + WS_LOSS);
    unsigned* ticket   = (unsigned*)(ws + WS_TICKET);
    float*    enorm    = (float*)(ws + WS_ENORM);
    bf16x8*   wsE      = (bf16x8*)(ws + WS_E);
    bf16x4*   wsE2     = (bf16x4*)(ws + WS_E);

    prep_e<<<256, 256, 0, stream>>>(e, enorm, wsE2, loss_acc, ticket);
    vq_main<<<512, 256, 0, stream>>>(z, e, enorm, wsE, out, loss_acc, ticket);
}

// Round 6
// 158.378 us; speedup vs baseline: 1.2537x; 1.2537x over previous
//
#include <hip/hip_runtime.h>
#include <hip/hip_bf16.h>

// Problem constants (from reference): z [65536,256] f32, embeddings [1024,256] f32
// out = quantized_st [65536*256] f32 ++ loss scalar (out_size = 16777217)
#define NROWS 65536
#define DIM   256
#define KCB   1024
#define ND    (NROWS * DIM)

typedef float f32x4  __attribute__((ext_vector_type(4)));
typedef short bf16x8 __attribute__((ext_vector_type(8)));  // 8 bf16 in 4 VGPRs
typedef short bf16x4 __attribute__((ext_vector_type(4)));  // 4 bf16 in 2 VGPRs

// workspace layout (bytes)
#define WS_LOSS   0      // float
#define WS_TICKET 64     // unsigned
#define WS_ENORM  256    // float[1024]
#define WS_E      8192   // bf16 permuted [16 chunks][2048 ids][8] = 512 KiB
// total needed: 8192 + 524288 = 532480 B

// fp32 -> bf16 bits, round-to-nearest-even
static __device__ __forceinline__ short f2bf(float f) {
    union { float f; unsigned u; } v; v.f = f;
    unsigned u = v.u;
    unsigned r = (u + 0x7fffu + ((u >> 16) & 1u)) >> 16;
    return (short)(unsigned short)r;
}

static __device__ __forceinline__ unsigned f2u(float f) {
    union { float f; unsigned u; } v; v.f = f; return v.u;
}
static __device__ __forceinline__ float u2f(unsigned u) {
    union { unsigned u; float f; } v; v.u = u; return v.f;
}

// ---------------------------------------------------------------------------
// Prep: e_norm (fp32) + E converted to bf16 in MFMA-staging-permuted order.
// Permuted id within a 64-row chunk: id = (t*8+s)*64 + q*16 + l
//   where embedding row = t*16+l, d-chunk c = s*4+q (8 bf16 per chunk).
// 256 blocks; each block owns 4 rows; each thread reads ONE coalesced
// float4 (16 B/lane), wave-reduces the row norm, writes its 8-B half-chunk.
// ---------------------------------------------------------------------------
__global__ __launch_bounds__(256) void prep_e(const float* __restrict__ E,
                                              float* __restrict__ enorm,
                                              bf16x4* __restrict__ wsE2,
                                              float* __restrict__ loss_acc,
                                              unsigned* __restrict__ ticket) {
    const int tid = threadIdx.x;
    const int blk = blockIdx.x;            // 0..255, 4 embedding rows each

    if (blk == 0 && tid == 0) { *loss_acc = 0.f; *ticket = 0u; }

    const int w    = tid >> 6;             // 0..3: row within this block
    const int lane = tid & 63;             // float4 index within the row
    const int row  = blk * 4 + w;

    float4 f = ((const float4*)E)[row * 64 + lane];

    // row norm: each wave holds exactly one row -> full-wave butterfly
    float s = f.x * f.x + f.y * f.y + f.z * f.z + f.w * f.w;
#pragma unroll
    for (int m = 1; m < 64; m <<= 1) s += __shfl_xor(s, m, 64);
    if (lane == 0) enorm[row] = s;

    // permuted bf16 half-chunk write (8 B per lane; lane pairs are 16-B contiguous)
    bf16x4 o;
    o[0] = f2bf(f.x); o[1] = f2bf(f.y); o[2] = f2bf(f.z); o[3] = f2bf(f.w);
    const int kc = row >> 6;               // 64-row chunk
    const int rg = row & 63;
    const int t  = rg >> 4, l = rg & 15;
    const int c    = lane >> 1;            // 8-elem d-chunk 0..31
    const int half = lane & 1;
    const int sC   = c >> 2, q = c & 3;
    const int id   = (t * 8 + sC) * 64 + q * 16 + l;
    wsE2[(kc * 2048 + id) * 2 + half] = o;
}

// ---------------------------------------------------------------------------
// Main: fused score-GEMM (bf16 MFMA) + argmin + gather + loss.
// Block = 256 thr (4 waves), 128 z-rows. Wave w owns rows w*32..w*32+31 as
// 2 row-tiles of 16; A-fragments live in registers for the whole K sweep.
//
// ROUND-6 synthesis of R0-R5 evidence:
//  * LDS staging is load-bearing (R5: per-wave L1/L2 streaming = 110 us,
//    2x worse — TA/TCP path can't amortize across waves; LDS can).
//  * Packed argmin keys verified (R5 passed, absmax 0.00195) and cut the
//    register file 120 -> 88: headroom under the measured 128-VGPR cliff.
//  * Pipeline failures diagnosed: R1 runtime-indexed LDS buffer (alias
//    serialization), R2 gll+136 VGPR, R3 loads issued immediately BEFORE a
//    barrier (whose vmcnt(0) drain exposes their latency) + 136 VGPR.
//  * Fix that dodges all three: STATIC double buffers Es0/Es1, reg-staged
//    copy, loads issued at the TOP of the compute phase (~2000 cycles of
//    ds_read+MFMA to hide under — a later barrier drain is then free),
//    ds_write at the END of compute, ONE barrier per chunk (16 vs 32).
//    VGPR: 88 base + 32 stg ~ 122 <= 128 -> 2 blocks/CU preserved.
// ---------------------------------------------------------------------------
__global__ __launch_bounds__(256, 2) void vq_main(const float* __restrict__ Z,
                                                  const float* __restrict__ E,
                                                  const float* __restrict__ enorm,
                                                  const bf16x8* __restrict__ wsE,
                                                  float* __restrict__ out,
                                                  float* __restrict__ loss_acc,
                                                  unsigned* __restrict__ ticket) {
    __shared__ bf16x8 Es0[2048];        // 32 KiB buffer A (even chunks)
    __shared__ bf16x8 Es1[2048];        // 32 KiB buffer B (odd chunks)
    __shared__ float  enorm_s[KCB];     // 4 KiB: all 1024 norms, pre-biased +1.0
    __shared__ float  znorm_s[128];
    __shared__ int    closest_s[128];
    __shared__ float  blk_loss;

    const int tid  = threadIdx.x;
    const int w    = tid >> 6;
    const int lane = tid & 63;
    const int q    = lane >> 4;
    const int l    = lane & 15;
    const int blk  = blockIdx.x;

    if (tid == 0) blk_loss = 0.f;

    // issue chunk-0 loads NOW; latency hides under enorm/zf loading below
    bf16x8 stg[8];
#pragma unroll
    for (int j = 0; j < 8; ++j) stg[j] = wsE[tid + 256 * j];

    // whole e-norm table once, biased by +1.0 for the positive-score trick
    {
        float4 e4 = ((const float4*)enorm)[tid];
        e4.x += 1.f; e4.y += 1.f; e4.z += 1.f; e4.w += 1.f;
        ((float4*)enorm_s)[tid] = e4;
    }

    // ---- load A fragments (z rows) into registers; accumulate ||z||^2 fp32 ----
    bf16x8 zf[2][8];
    const float4* Z4 = (const float4*)Z;
#pragma unroll
    for (int rt = 0; rt < 2; ++rt) {
        int row = blk * 128 + w * 32 + rt * 16 + l;
        float zn = 0.f;
#pragma unroll
        for (int s = 0; s < 8; ++s) {
            int fi = row * 64 + s * 8 + q * 2;
            float4 f0 = Z4[fi], f1 = Z4[fi + 1];
            zn += f0.x * f0.x + f0.y * f0.y + f0.z * f0.z + f0.w * f0.w;
            zn += f1.x * f1.x + f1.y * f1.y + f1.z * f1.z + f1.w * f1.w;
            bf16x8 o;
            o[0] = f2bf(f0.x); o[1] = f2bf(f0.y); o[2] = f2bf(f0.z); o[3] = f2bf(f0.w);
            o[4] = f2bf(f1.x); o[5] = f2bf(f1.y); o[6] = f2bf(f1.z); o[7] = f2bf(f1.w);
            zf[rt][s] = o;
        }
        // each lane holds 64 of the row's 256 values; sum across the 4 q-lanes
        zn += __shfl_xor(zn, 16, 64);
        zn += __shfl_xor(zn, 32, 64);
        if (q == 0) znorm_s[w * 32 + rt * 16 + l] = zn;
    }

    // packed running argmin: high 22 bits = biased-score bits, low 10 = kidx
    unsigned minp[2][4];
#pragma unroll
    for (int rt = 0; rt < 2; ++rt)
#pragma unroll
        for (int r = 0; r < 4; ++r) minp[rt][r] = 0xFFFFFFFFu;

    // commit chunk 0 to Es0 (implicit s_waitcnt vmcnt before first ds_write)
#pragma unroll
    for (int j = 0; j < 8; ++j) Es0[tid + 256 * j] = stg[j];
    __syncthreads();   // Es0 + enorm_s + blk_loss visible to all waves

    // issue next-chunk global loads into registers (top of compute phase)
#define PREF(KN)                                                             \
    _Pragma("unroll")                                                        \
    for (int j = 0; j < 8; ++j) stg[j] = wsE[(KN) * 2048 + tid + 256 * j];

    // commit staged registers into the other LDS buffer (end of compute)
#define COMMIT(EDST)                                                         \
    _Pragma("unroll")                                                        \
    for (int j = 0; j < 8; ++j) (EDST)[tid + 256 * j] = stg[j];

    // compute one 64-embedding chunk from ESRC; update running packed argmin
#define COMPUTE(ESRC, KC)                                                    \
    {                                                                        \
        f32x4 acc[2][4];                                                     \
        _Pragma("unroll")                                                    \
        for (int rt = 0; rt < 2; ++rt)                                       \
            _Pragma("unroll")                                                \
            for (int t = 0; t < 4; ++t) acc[rt][t] = (f32x4){0.f,0.f,0.f,0.f};\
        _Pragma("unroll")                                                    \
        for (int s = 0; s < 8; ++s) {                                        \
            bf16x8 b0 = (ESRC)[(0 * 8 + s) * 64 + lane];                     \
            bf16x8 b1 = (ESRC)[(1 * 8 + s) * 64 + lane];                     \
            bf16x8 b2 = (ESRC)[(2 * 8 + s) * 64 + lane];                     \
            bf16x8 b3 = (ESRC)[(3 * 8 + s) * 64 + lane];                     \
            acc[0][0] = __builtin_amdgcn_mfma_f32_16x16x32_bf16(zf[0][s], b0, acc[0][0], 0, 0, 0); \
            acc[0][1] = __builtin_amdgcn_mfma_f32_16x16x32_bf16(zf[0][s], b1, acc[0][1], 0, 0, 0); \
            acc[0][2] = __builtin_amdgcn_mfma_f32_16x16x32_bf16(zf[0][s], b2, acc[0][2], 0, 0, 0); \
            acc[0][3] = __builtin_amdgcn_mfma_f32_16x16x32_bf16(zf[0][s], b3, acc[0][3], 0, 0, 0); \
            acc[1][0] = __builtin_amdgcn_mfma_f32_16x16x32_bf16(zf[1][s], b0, acc[1][0], 0, 0, 0); \
            acc[1][1] = __builtin_amdgcn_mfma_f32_16x16x32_bf16(zf[1][s], b1, acc[1][1], 0, 0, 0); \
            acc[1][2] = __builtin_amdgcn_mfma_f32_16x16x32_bf16(zf[1][s], b2, acc[1][2], 0, 0, 0); \
            acc[1][3] = __builtin_amdgcn_mfma_f32_16x16x32_bf16(zf[1][s], b3, acc[1][3], 0, 0, 0); \
        }                                                                    \
        /* C/D layout: col = lane&15 (embedding), row = q*4+reg (z row) */   \
        /* sc' = (en+1) - 2*dot in (0.4,1.6): u32 order == f32 order */      \
        _Pragma("unroll")                                                    \
        for (int t = 0; t < 4; ++t) {                                        \
            float    en   = enorm_s[(KC) * 64 + t * 16 + l];                 \
            unsigned kidx = (unsigned)((KC) * 64 + t * 16 + l);              \
            _Pragma("unroll")                                                \
            for (int rt = 0; rt < 2; ++rt)                                   \
                _Pragma("unroll")                                            \
                for (int r = 0; r < 4; ++r) {                                \
                    float sc = __builtin_fmaf(-2.f, acc[rt][t][r], en);      \
                    unsigned key = (f2u(sc) & 0xFFFFFC00u) | kidx;           \
                    minp[rt][r] = key < minp[rt][r] ? key : minp[rt][r];     \
                }                                                            \
        }                                                                    \
    }

    // ---- K sweep: 1-deep pipeline, ONE barrier per chunk ----
    for (int kk = 0; kk < 8; ++kk) {
        const int k0 = kk * 2;
        // even chunk from Es0; prefetch odd chunk; commit it to Es1
        PREF(k0 + 1)
        COMPUTE(Es0, k0)
        COMMIT(Es1)
        __syncthreads();                 // Es1 ready; Es0 free
        // odd chunk from Es1; prefetch next even chunk; commit it to Es0
        if (kk < 7) { PREF(k0 + 2) }
        COMPUTE(Es1, k0 + 1)
        if (kk < 7) { COMMIT(Es0) }
        __syncthreads();                 // Es0 ready; Es1 free
    }
#undef PREF
#undef COMMIT
#undef COMPUTE

    // ---- cross-lane argmin: u32 min over the 16 column-lanes of each quad ----
    float lossp = 0.f;
#pragma unroll
    for (int rt = 0; rt < 2; ++rt)
#pragma unroll
        for (int r = 0; r < 4; ++r) {
            unsigned p = minp[rt][r];
#pragma unroll
            for (int m = 1; m <= 8; m <<= 1) {
                unsigned op = (unsigned)__shfl_xor((int)p, m, 64);
                p = op < p ? op : p;
            }
            if (l == 0) {
                int rloc = w * 32 + rt * 16 + q * 4 + r;
                closest_s[rloc] = (int)(p & 1023u);
                float v = u2f(p & 0xFFFFFC00u) - 1.0f;
                lossp += v + znorm_s[rloc];   // ||z||^2 + ||e*||^2 - 2 z.e*
            }
        }
    if (l == 0) atomicAdd(&blk_loss, lossp);
    __syncthreads();                      // closest_s + blk_loss visible

    // ---- gather epilogue: out rows = E[closest] in fp32 (exact values) ----
    const float4* E4 = (const float4*)E;
    float4* O4 = (float4*)out;
#pragma unroll
    for (int u = 0; u < 32; ++u) {
        int idx = u * 256 + tid;          // 0..8191
        int row = idx >> 6;
        int c4  = idx & 63;
        int k   = closest_s[row];
        O4[(blk * 128 + row) * 64 + c4] = E4[k * 64 + c4];
    }

    // ---- loss finalize: last block through the ticket writes the scalar ----
    if (tid == 0) {
        atomicAdd(loss_acc, blk_loss);
        __threadfence();                  // loss add visible before ticket bump
        unsigned tk = atomicAdd(ticket, 1u);
        if (tk == (unsigned)(gridDim.x - 1)) {
            float total = atomicAdd(loss_acc, 0.0f);   // coherent read of final sum
            out[ND] = 1.25f * total / (float)ND;       // codebook + 0.25*commitment
        }
    }
}

extern "C" void kernel_launch(void* const* d_in, const int* in_sizes, int n_in,
                              void* d_out, int out_size, void* d_ws, size_t ws_size,
                              hipStream_t stream) {
    const float* z = (const float*)d_in[0];
    const float* e = (const float*)d_in[1];
    float* out = (float*)d_out;
    char*  ws  = (char*)d_ws;
    float*    loss_acc = (float*)(ws + WS_LOSS);
    unsigned* ticket   = (unsigned*)(ws + WS_TICKET);
    float*    enorm    = (float*)(ws + WS_ENORM);
    bf16x8*   wsE      = (bf16x8*)(ws + WS_E);
    bf16x4*   wsE2     = (bf16x4*)(ws + WS_E);

    prep_e<<<256, 256, 0, stream>>>(e, enorm, wsE2, loss_acc, ticket);
    vq_main<<<512, 256, 0, stream>>>(z, e, enorm, wsE, out, loss_acc, ticket);
}